// Round 10
// baseline (205.772 us; speedup 1.0000x reference)
//
#include <hip/hip_runtime.h>
#include <math.h>

#define SPB 3136      // spatial positions per batch (56*56)
#define NB 8
#define MTOT (NB*SPB) // 25088 = 196*128, flattened M across batch
#define EPS 1e-5f
// padded leading dims (u16 elems): +32 bf16 = +64B so row strides are ODD
// multiples of 64B -> walk all L2 channels (break 512B/1KB channel aliasing)
#define XT_LD  288    // xt rows (K=256)
#define CAT_LD 544    // catt/gt rows (K=512)

typedef unsigned short u16;
typedef __attribute__((ext_vector_type(8))) short short8;
typedef __attribute__((ext_vector_type(4))) float float4v;

__device__ __forceinline__ float b2f(u16 v){ unsigned u=((unsigned)v)<<16; float f; __builtin_memcpy(&f,&u,4); return f; }
__device__ __forceinline__ u16 f2b(float f){ unsigned u; __builtin_memcpy(&u,&f,4); u += 0x7fffu + ((u>>16)&1u); return (u16)(u>>16); }
// tanh-approx GELU via sigmoid
__device__ __forceinline__ float gelu_f(float z){
  float t = 1.5957691216f * z * (1.0f + 0.044715f*z*z);
  return __fdividef(z, 1.0f + __expf(-t));
}

// async global->LDS, 16B per lane; lds dest must be wave-uniform base + lane*16
__device__ __forceinline__ void gll16(const u16* g, u16* l){
  __builtin_amdgcn_global_load_lds((const __attribute__((address_space(1))) void*)g,
                                   (__attribute__((address_space(3))) void*)l, 16, 0, 0);
}

// ---- fused prep: x transpose (blocks z<8) + weight bf16 (PADDED rows) + BN consts (z>=8) ----
// cst layout: s1[256] t1[256] sg[512] tg[512] s2[256] t2[256]
__global__ void prep_k(const float* __restrict__ x, u16* __restrict__ xt,
                       const float* __restrict__ w1,const float* __restrict__ wg,const float* __restrict__ w2,
                       const float* b1,const float* g1,const float* be1,const float* m1,const float* v1,
                       const float* bg,const float* gg,const float* beg,const float* mg,const float* vg,
                       const float* b2,const float* g2,const float* be2,const float* m2,const float* v2,
                       u16* __restrict__ w1b,u16* __restrict__ wgb,u16* __restrict__ w2b,float* cst){
  __shared__ float t[32][33];
  if (blockIdx.z < 8) {
    int b = blockIdx.z, ct = blockIdx.y, st = blockIdx.x;
    int ts = threadIdx.x, tc = threadIdx.y;
    #pragma unroll
    for (int i=0;i<4;i++){
      int c = tc + i*8;
      t[c][ts] = x[((size_t)(b*256 + ct*32 + c))*SPB + st*32 + ts];
    }
    __syncthreads();
    #pragma unroll
    for (int i=0;i<4;i++){
      int r = tc + i*8;
      xt[((size_t)(b*SPB + st*32 + r))*XT_LD + ct*32 + ts] = f2b(t[ts][r]);
    }
  } else {
    int tid = threadIdx.y*32 + threadIdx.x;
    int w = ((blockIdx.z-8)*8 + blockIdx.y)*98 + blockIdx.x;   // [0, 1568)
    int i = w*256 + tid;
    if (i < 65536)  w1b[(i>>8)*XT_LD  + (i&255)] = f2b(w1[i]);   // [256][256] -> LD 288
    if (i < 262144) wgb[(i>>9)*CAT_LD + (i&511)] = f2b(wg[i]);   // [512][512] -> LD 544
    if (i < 131072) w2b[(i>>9)*CAT_LD + (i&511)] = f2b(w2[i]);   // [256][512] -> LD 544
    if (i < 256) {
      float s = g1[i]*rsqrtf(v1[i]+EPS);
      cst[i] = s; cst[256+i] = b1[i]*s + be1[i] - m1[i]*s;
      float s2 = g2[i]*rsqrtf(v2[i]+EPS);
      cst[1536+i] = s2; cst[1792+i] = b2[i]*s2 + be2[i] - m2[i]*s2;
    }
    if (i < 512) {
      float s = gg[i]*rsqrtf(vg[i]+EPS);
      cst[512+i] = s; cst[1024+i] = bg[i]*s + beg[i] - mg[i]*s;
    }
  }
}

// ---- FUSED parity-min + xj: one pass over h instead of three ----
// Block = (c-chunk of 8 channels, batch b). 448 threads, 7 spatial positions each.
// 1) stage h[3136][8ch] in LDS (50KB, one strided global read of h)
// 2) compute rowmin[y][parx][k] and colmin[x][pary][k] in LDS (896 scalars each,
//    2 per thread, 28-deep fmin chains over LDS)
// 3) xj[s][k] = relu(h - min(colmin[x][y&1], rowmin[y][x&1])) -> cat[...,256:512]
// Parity-min including j==self is idempotent under the relu (h-min<=0 -> 0).
__global__ __launch_bounds__(448) void hxj_k(u16* __restrict__ cat){
  __shared__ u16 hl[SPB*8];            // [s][k] 50176 B
  __shared__ float rowm[56][2][8];     // [y][x-parity][k] 3584 B
  __shared__ float colm[56][2][8];     // [x][y-parity][k] 3584 B
  const int b = blockIdx.y;
  const int c0 = blockIdx.x * 8;
  const int t = threadIdx.x;
  const size_t base = (size_t)b*SPB*CAT_LD + c0;
  #pragma unroll
  for (int i=0;i<7;i++){
    int s = i*448 + t;
    *(short8*)&hl[s*8] = *(const short8*)&cat[base + (size_t)s*CAT_LD];
  }
  __syncthreads();
  #pragma unroll
  for (int half=0; half<2; half++){
    int id = half*448 + t;             // 0..895
    int a = id >> 4;                   // y (row pass) / x (col pass), 0..55
    int par = (id >> 3) & 1;
    int k = id & 7;
    float mr = 3.4e38f, mc = 3.4e38f;
    #pragma unroll
    for (int j=0;j<28;j++){
      int u = par + j*2;
      mr = fminf(mr, b2f(hl[(a*56 + u)*8 + k]));   // min over x'=u, fixed y=a
      mc = fminf(mc, b2f(hl[(u*56 + a)*8 + k]));   // min over y'=u, fixed x=a
    }
    rowm[a][par][k] = mr;
    colm[a][par][k] = mc;
  }
  __syncthreads();
  #pragma unroll
  for (int i=0;i<7;i++){
    int s = i*448 + t;
    int y = s/56, x = s - y*56;
    short8 h8 = *(const short8*)&hl[s*8];
    short8 o;
    #pragma unroll
    for (int k=0;k<8;k++){
      float m = fminf(colm[x][y&1][k], rowm[y][x&1][k]);
      o[k] = (short)f2b(fmaxf(0.0f, b2f((u16)h8[k]) - m));
    }
    *(short8*)&cat[base + (size_t)s*CAT_LD + 256] = o;
  }
}

// bijective XCD-chunk remap (T1, m204); all gemm grids are %8==0
__device__ __forceinline__ int xcd_remap(int orig, int nwg){
  int q = nwg >> 3, r = nwg & 7, xc = orig & 7, rest = orig >> 3;
  int base = (xc < r) ? xc*(q+1) : r*(q+1) + (xc-r)*q;
  return base + rest;
}

// GEMM: D[m][o] = sum_k Ain[m][k]*Wt[o][k]; padded LDA/LDB.
// BK=64 (R9: fewer barriers, -2us) COMBINED with counted-vmcnt depth-2
// (R3: -9us): 3 bufs x 32KB = 96KB LDS -> 1 block/CU (8 waves/CU; R8 showed
// TLP beyond this is not binding). Per iter:
//   sched_barrier; s_waitcnt vmcnt(4) lgkmcnt(0); s_barrier; sched_barrier;
//   STAGE(t+2) -> buf (t+2)%3; COMPUTE(t) -> buf t%3
// vmcnt(4): stage(t) drained (oldest), stage(t+1)'s 4 loads stay in flight
// across the barrier. lgkmcnt(0) pre-barrier: COMPUTE(t-1)'s reads of
// buf (t-1)%3 (= the buf STAGE(t+2) overwrites) complete first (R3 discipline).
// Staging (8 slots/row): thread t -> rows (t>>3), 64+(t>>3), slot t&7;
// gll16 dest = tid*16B (lane-linear). T2 both-sides: source chunk
// (t&7)^((t>>3)&7); read slot (kk*4+quad)^(l16&7). Row terms = 0 mod 8.
// EPI 1: bf16(acc*s+t)        -> out [m][CAT_LD] at col o0
// EPI 2: bf16(gelu(acc*s+t))  -> out [m][CAT_LD] at col o0
// EPI 3: fp32(acc*s+t + resid[b][o][s]) -> out [b][256][s]
template<int KTOT, int LDA, int LDB, int EPI>
__global__ __launch_bounds__(512,2) void gemm_k(
    const u16* __restrict__ Ain, const u16* __restrict__ Wt,
    const float* __restrict__ scale, const float* __restrict__ bias,
    void* __restrict__ outp, const float* __restrict__ resid)
{
  __shared__ __align__(16) u16 smem[49152];   // 98304 B: 3 x 32KB staging / epilogue union
  const int tid = threadIdx.x;
  const int nwg = gridDim.x * gridDim.y;
  const int flat = blockIdx.y * gridDim.x + blockIdx.x;
  const int s_ = xcd_remap(flat, nwg);
  const int m0 = (s_ / gridDim.y) * 128;
  const int o0 = (s_ % gridDim.y) * 128;
  const int lane = tid & 63, wid = tid >> 6;     // 8 waves
  const int quad = lane >> 4, l16 = lane & 15;

  float4v acc[8];
  #pragma unroll
  for (int j=0;j<8;j++) acc[j] = (float4v){0.f,0.f,0.f,0.f};

  // staging buf at smem + buf*16384 (u16): A [128][64] +0, B [128][64] +8192.
  const int row8 = tid >> 3;                       // 0..63
  const int gc   = ((tid & 7) ^ (row8 & 7)) * 8;   // T2 source chunk (u16 off)
  const u16* ga0 = Ain + ((size_t)(m0 + row8))*LDA + gc;
  const u16* ga1 = ga0 + (size_t)64*LDA;
  const u16* gb0 = Wt  + ((size_t)(o0 + row8))*LDB + gc;
  const u16* gb1 = gb0 + (size_t)64*LDB;
  u16* l8 = smem + tid*8;

  auto STAGE = [&](int kt, int buf){
    u16* b_ = l8 + buf*16384;
    gll16(ga0 + kt, b_);
    gll16(ga1 + kt, b_ + 4096);
    gll16(gb0 + kt, b_ + 8192);
    gll16(gb1 + kt, b_ + 12288);
  };
  const int r7 = l16 & 7;                          // read-row & 7 (all frag rows)
  auto COMPUTE = [&](int buf){
    const u16* A_ = smem + buf*16384;
    const u16* B_ = A_ + 8192;
    #pragma unroll
    for (int kk=0; kk<2; kk++){
      const int sl = ((kk*4 + quad) ^ r7) * 8;
      short8 af = *(const short8*)&A_[(wid*16 + l16)*64 + sl];
      short8 bfr[8];
      #pragma unroll
      for (int in=0;in<8;in++) bfr[in] = *(const short8*)&B_[(in*16+l16)*64 + sl];
      #pragma unroll
      for (int in=0;in<8;in++)
        acc[in] = __builtin_amdgcn_mfma_f32_16x16x32_bf16(af, bfr[in], acc[in], 0, 0, 0);
    }
  };

  constexpr int NIT = KTOT / 64;
  STAGE(0, 0);
  STAGE(64, 1);
  #pragma unroll
  for (int t = 0; t < NIT; ++t) {
    __builtin_amdgcn_sched_barrier(0);
    if (t + 1 < NIT) asm volatile("s_waitcnt vmcnt(4) lgkmcnt(0)" ::: "memory");
    else             asm volatile("s_waitcnt vmcnt(0) lgkmcnt(0)" ::: "memory");
    __builtin_amdgcn_s_barrier();
    __builtin_amdgcn_sched_barrier(0);
    if (t + 2 < NIT) STAGE((t+2)*64, (t+2)%3);
    COMPUTE(t%3);
  }
  __syncthreads();            // staging bufs free -> smem reuse for epilogue

  if (EPI == 1 || EPI == 2) {
    u16* tile = smem; // [128 m][128 o], 32KB
    #pragma unroll
    for (int in=0;in<8;in++){
      int ol = in*16 + l16;
      float sc = scale[o0+ol], bi = bias[o0+ol];
      #pragma unroll
      for (int r=0;r<4;r++){
        float v = acc[in][r]*sc + bi;
        if (EPI==2) v = gelu_f(v);
        tile[(wid*16+quad*4+r)*128 + ol] = f2b(v);
      }
    }
    __syncthreads();
    u16* op = (u16*)outp;
    #pragma unroll
    for (int p=0;p<4;p++){
      int chunk = p*512 + tid;
      int rr = chunk >> 4, off = (chunk & 15)*8;
      *(uint4*)&op[((size_t)(m0 + rr))*CAT_LD + o0 + off] = *(const uint4*)&tile[rr*128 + off];
    }
  } else {
    float* ftile = (float*)smem; // [64 o][132 m] fp32 = 33792B, one half at a time
    float* op = (float*)outp;
    #pragma unroll
    for (int h=0; h<2; h++){
      #pragma unroll
      for (int in4=0;in4<4;in4++){
        int in = h*4 + in4;
        int c64 = in4*16 + l16;
        int og = o0 + h*64 + c64;
        float sc = scale[og], bi = bias[og];
        float4v v;
        #pragma unroll
        for (int r=0;r<4;r++) v[r] = acc[in][r]*sc + bi;
        *(float4v*)&ftile[c64*132 + wid*16 + quad*4] = v;
      }
      __syncthreads();
      #pragma unroll
      for (int p=0;p<4;p++){
        int chunk = p*512 + tid;
        int rr = chunk >> 5, off = (chunk & 31)*4;
        int m = m0 + off;
        int b = m / SPB, s = m - b*SPB;
        size_t g = ((size_t)(b*256 + o0 + h*64 + rr))*SPB + s;
        float4v v = *(const float4v*)&ftile[rr*132 + off];
        v.x += resid[g]; v.y += resid[g+1]; v.z += resid[g+2]; v.w += resid[g+3];
        *(float4v*)&op[g] = v;
      }
      __syncthreads();
    }
  }
}

extern "C" void kernel_launch(void* const* d_in, const int* in_sizes, int n_in,
                              void* d_out, int out_size, void* d_ws, size_t ws_size,
                              hipStream_t stream)
{
  const float* x  = (const float*)d_in[0];
  const float* w1 = (const float*)d_in[1];
  const float* b1 = (const float*)d_in[2];
  const float* g1 = (const float*)d_in[3];
  const float* be1= (const float*)d_in[4];
  const float* m1 = (const float*)d_in[5];
  const float* v1 = (const float*)d_in[6];
  const float* wg = (const float*)d_in[7];
  const float* bg = (const float*)d_in[8];
  const float* gg = (const float*)d_in[9];
  const float* beg= (const float*)d_in[10];
  const float* mg = (const float*)d_in[11];
  const float* vg = (const float*)d_in[12];
  const float* w2 = (const float*)d_in[13];
  const float* b2 = (const float*)d_in[14];
  const float* g2 = (const float*)d_in[15];
  const float* be2= (const float*)d_in[16];
  const float* m2 = (const float*)d_in[17];
  const float* v2 = (const float*)d_in[18];

  char* ws = (char*)d_ws;
  size_t off = 0;
  auto alloc = [&](size_t bytes){ void* p = ws + off; off += (bytes + 255) & ~(size_t)255; return p; };
  u16* xt    = (u16*)alloc((size_t)MTOT*XT_LD*2);    // x transposed, bf16, padded
  u16* catt  = (u16*)alloc((size_t)MTOT*CAT_LD*2);   // [h ; xj], bf16, padded
  u16* gt    = (u16*)alloc((size_t)MTOT*CAT_LD*2);   // gelu output, bf16, padded
  u16* w1b   = (u16*)alloc((size_t)256*XT_LD*2);
  u16* wgb   = (u16*)alloc((size_t)512*CAT_LD*2);
  u16* w2b   = (u16*)alloc((size_t)256*CAT_LD*2);
  float* cst = (float*)alloc((size_t)2048*4);

  hipLaunchKernelGGL(prep_k, dim3(98,8,10), dim3(32,8), 0, stream,
                     x, xt, w1,wg,w2, b1,g1,be1,m1,v1, bg,gg,beg,mg,vg, b2,g2,be2,m2,v2,
                     w1b,wgb,w2b, cst);
  hipLaunchKernelGGL((gemm_k<256,XT_LD,XT_LD,1>), dim3(196,2), dim3(512), 0, stream,
                     xt, w1b, cst+0, cst+256, (void*)catt, (const float*)nullptr);
  hipLaunchKernelGGL(hxj_k, dim3(32, NB), dim3(448), 0, stream, catt);
  hipLaunchKernelGGL((gemm_k<512,CAT_LD,CAT_LD,2>), dim3(196,4), dim3(512), 0, stream,
                     catt, wgb, cst+512, cst+1024, (void*)gt, (const float*)nullptr);
  hipLaunchKernelGGL((gemm_k<512,CAT_LD,CAT_LD,3>), dim3(196,2), dim3(512), 0, stream,
                     gt, w2b, cst+1536, cst+1792, d_out, x);
}

// Round 11
// 190.107 us; speedup vs baseline: 1.0824x; 1.0824x over previous
//
#include <hip/hip_runtime.h>
#include <math.h>

#define SPB 3136      // spatial positions per batch (56*56)
#define NB 8
#define MTOT (NB*SPB) // 25088 = 196*128, flattened M across batch
#define EPS 1e-5f
// padded leading dims (u16 elems): +32 bf16 = +64B so row strides are ODD
// multiples of 64B -> walk all L2 channels (break 512B/1KB channel aliasing)
#define XT_LD  288    // xt rows (K=256)
#define CAT_LD 544    // catt/gt rows (K=512)

typedef unsigned short u16;
typedef __attribute__((ext_vector_type(8))) short short8;
typedef __attribute__((ext_vector_type(4))) float float4v;

__device__ __forceinline__ float b2f(u16 v){ unsigned u=((unsigned)v)<<16; float f; __builtin_memcpy(&f,&u,4); return f; }
__device__ __forceinline__ u16 f2b(float f){ unsigned u; __builtin_memcpy(&u,&f,4); u += 0x7fffu + ((u>>16)&1u); return (u16)(u>>16); }
// tanh-approx GELU via sigmoid
__device__ __forceinline__ float gelu_f(float z){
  float t = 1.5957691216f * z * (1.0f + 0.044715f*z*z);
  return __fdividef(z, 1.0f + __expf(-t));
}

// async global->LDS, 16B per lane; lds dest must be wave-uniform base + lane*16
__device__ __forceinline__ void gll16(const u16* g, u16* l){
  __builtin_amdgcn_global_load_lds((const __attribute__((address_space(1))) void*)g,
                                   (__attribute__((address_space(3))) void*)l, 16, 0, 0);
}

// ---- fused prep: x transpose (blocks z<8) + weight bf16 (PADDED rows) + BN consts (z>=8) ----
// cst layout: s1[256] t1[256] sg[512] tg[512] s2[256] t2[256]
__global__ void prep_k(const float* __restrict__ x, u16* __restrict__ xt,
                       const float* __restrict__ w1,const float* __restrict__ wg,const float* __restrict__ w2,
                       const float* b1,const float* g1,const float* be1,const float* m1,const float* v1,
                       const float* bg,const float* gg,const float* beg,const float* mg,const float* vg,
                       const float* b2,const float* g2,const float* be2,const float* m2,const float* v2,
                       u16* __restrict__ w1b,u16* __restrict__ wgb,u16* __restrict__ w2b,float* cst){
  __shared__ float t[32][33];
  if (blockIdx.z < 8) {
    int b = blockIdx.z, ct = blockIdx.y, st = blockIdx.x;
    int ts = threadIdx.x, tc = threadIdx.y;
    #pragma unroll
    for (int i=0;i<4;i++){
      int c = tc + i*8;
      t[c][ts] = x[((size_t)(b*256 + ct*32 + c))*SPB + st*32 + ts];
    }
    __syncthreads();
    #pragma unroll
    for (int i=0;i<4;i++){
      int r = tc + i*8;
      xt[((size_t)(b*SPB + st*32 + r))*XT_LD + ct*32 + ts] = f2b(t[ts][r]);
    }
  } else {
    int tid = threadIdx.y*32 + threadIdx.x;
    int w = ((blockIdx.z-8)*8 + blockIdx.y)*98 + blockIdx.x;   // [0, 1568)
    int i = w*256 + tid;
    if (i < 65536)  w1b[(i>>8)*XT_LD  + (i&255)] = f2b(w1[i]);   // [256][256] -> LD 288
    if (i < 262144) wgb[(i>>9)*CAT_LD + (i&511)] = f2b(wg[i]);   // [512][512] -> LD 544
    if (i < 131072) w2b[(i>>9)*CAT_LD + (i&511)] = f2b(w2[i]);   // [256][512] -> LD 544
    if (i < 256) {
      float s = g1[i]*rsqrtf(v1[i]+EPS);
      cst[i] = s; cst[256+i] = b1[i]*s + be1[i] - m1[i]*s;
      float s2 = g2[i]*rsqrtf(v2[i]+EPS);
      cst[1536+i] = s2; cst[1792+i] = b2[i]*s2 + be2[i] - m2[i]*s2;
    }
    if (i < 512) {
      float s = gg[i]*rsqrtf(vg[i]+EPS);
      cst[512+i] = s; cst[1024+i] = bg[i]*s + beg[i] - mg[i]*s;
    }
  }
}

// ---- FUSED parity-min + xj (verified R10): one pass over h instead of three ----
// Block = (c-chunk of 8 channels, batch b). 448 threads, 7 spatial positions each.
// 1) stage h[3136][8ch] in LDS (50KB, one strided global read of h)
// 2) rowmin[y][parx][k], colmin[x][pary][k] in LDS (2 per thread, 28-deep chains)
// 3) xj[s][k] = relu(h - min(colmin[x][y&1], rowmin[y][x&1])) -> cat[...,256:512]
// Parity-min including j==self is idempotent under the relu (h-min<=0 -> 0).
__global__ __launch_bounds__(448) void hxj_k(u16* __restrict__ cat){
  __shared__ u16 hl[SPB*8];            // [s][k] 50176 B
  __shared__ float rowm[56][2][8];     // [y][x-parity][k] 3584 B
  __shared__ float colm[56][2][8];     // [x][y-parity][k] 3584 B
  const int b = blockIdx.y;
  const int c0 = blockIdx.x * 8;
  const int t = threadIdx.x;
  const size_t base = (size_t)b*SPB*CAT_LD + c0;
  #pragma unroll
  for (int i=0;i<7;i++){
    int s = i*448 + t;
    *(short8*)&hl[s*8] = *(const short8*)&cat[base + (size_t)s*CAT_LD];
  }
  __syncthreads();
  #pragma unroll
  for (int half=0; half<2; half++){
    int id = half*448 + t;             // 0..895
    int a = id >> 4;                   // y (row pass) / x (col pass), 0..55
    int par = (id >> 3) & 1;
    int k = id & 7;
    float mr = 3.4e38f, mc = 3.4e38f;
    #pragma unroll
    for (int j=0;j<28;j++){
      int u = par + j*2;
      mr = fminf(mr, b2f(hl[(a*56 + u)*8 + k]));   // min over x'=u, fixed y=a
      mc = fminf(mc, b2f(hl[(u*56 + a)*8 + k]));   // min over y'=u, fixed x=a
    }
    rowm[a][par][k] = mr;
    colm[a][par][k] = mc;
  }
  __syncthreads();
  #pragma unroll
  for (int i=0;i<7;i++){
    int s = i*448 + t;
    int y = s/56, x = s - y*56;
    short8 h8 = *(const short8*)&hl[s*8];
    short8 o;
    #pragma unroll
    for (int k=0;k<8;k++){
      float m = fminf(colm[x][y&1][k], rowm[y][x&1][k]);
      o[k] = (short)f2b(fmaxf(0.0f, b2f((u16)h8[k]) - m));
    }
    *(short8*)&cat[base + (size_t)s*CAT_LD + 256] = o;
  }
}

// bijective XCD-chunk remap (T1, m204); all gemm grids are %8==0
__device__ __forceinline__ int xcd_remap(int orig, int nwg){
  int q = nwg >> 3, r = nwg & 7, xc = orig & 7, rest = orig >> 3;
  int base = (xc < r) ? xc*(q+1) : r*(q+1) + (xc-r)*q;
  return base + rest;
}

// GEMM (REVERTED to R9-verified 177.6us config): BK=64, 2 bufs x 32KB = 64KB
// -> 2 blocks/CU (inter-block overlap covers the barrier drain -- R10 proved
// 1 block/CU loses ~12us/gemm).  BM=BN=128, 512 thr = 8 waves, wave 16m x 128o.
//   top of iter: sched_barrier; vmcnt(0) lgkmcnt(0); s_barrier; sched_barrier;
//   then STAGE(t+1) -> buf (t+1)&1; COMPUTE(t) -> buf t&1.
// lgkmcnt(0) before barrier: COMPUTE(t-1)'s reads of buf (t-1)&1 (= the buf
// STAGE(t+1) overwrites) complete before any wave crosses (R3 discipline).
// Staging (8 slots/row): thread t -> rows (t>>3), 64+(t>>3), slot t&7;
// gll16 dest = tid*16B (lane-linear). T2 both-sides: source chunk
// (t&7)^((t>>3)&7); read slot (kk*4+quad)^(l16&7). Row terms = 0 mod 8.
// EPI 1: bf16(acc*s+t)        -> out [m][CAT_LD] at col o0
// EPI 2: bf16(gelu(acc*s+t))  -> out [m][CAT_LD] at col o0
// EPI 3: fp32(acc*s+t + resid[b][o][s]) -> out [b][256][s]
template<int KTOT, int LDA, int LDB, int EPI>
__global__ __launch_bounds__(512,4) void gemm_k(
    const u16* __restrict__ Ain, const u16* __restrict__ Wt,
    const float* __restrict__ scale, const float* __restrict__ bias,
    void* __restrict__ outp, const float* __restrict__ resid)
{
  __shared__ __align__(16) u16 smem[32768];   // 65536 B: 2 x 32KB staging / epilogue union
  const int tid = threadIdx.x;
  const int nwg = gridDim.x * gridDim.y;
  const int flat = blockIdx.y * gridDim.x + blockIdx.x;
  const int s_ = xcd_remap(flat, nwg);
  const int m0 = (s_ / gridDim.y) * 128;
  const int o0 = (s_ % gridDim.y) * 128;
  const int lane = tid & 63, wid = tid >> 6;     // 8 waves
  const int quad = lane >> 4, l16 = lane & 15;

  float4v acc[8];
  #pragma unroll
  for (int j=0;j<8;j++) acc[j] = (float4v){0.f,0.f,0.f,0.f};

  // staging buf at smem + buf*16384 (u16): A [128][64] +0, B [128][64] +8192.
  const int row8 = tid >> 3;                       // 0..63
  const int gc   = ((tid & 7) ^ (row8 & 7)) * 8;   // T2 source chunk (u16 off)
  const u16* ga0 = Ain + ((size_t)(m0 + row8))*LDA + gc;
  const u16* ga1 = ga0 + (size_t)64*LDA;
  const u16* gb0 = Wt  + ((size_t)(o0 + row8))*LDB + gc;
  const u16* gb1 = gb0 + (size_t)64*LDB;
  u16* l8 = smem + tid*8;

  auto STAGE = [&](int kt, int buf){
    u16* b_ = l8 + buf*16384;
    gll16(ga0 + kt, b_);
    gll16(ga1 + kt, b_ + 4096);
    gll16(gb0 + kt, b_ + 8192);
    gll16(gb1 + kt, b_ + 12288);
  };
  const int r7 = l16 & 7;                          // read-row & 7 (all frag rows)
  auto COMPUTE = [&](int buf){
    const u16* A_ = smem + buf*16384;
    const u16* B_ = A_ + 8192;
    #pragma unroll
    for (int kk=0; kk<2; kk++){
      const int sl = ((kk*4 + quad) ^ r7) * 8;
      short8 af = *(const short8*)&A_[(wid*16 + l16)*64 + sl];
      short8 bfr[8];
      #pragma unroll
      for (int in=0;in<8;in++) bfr[in] = *(const short8*)&B_[(in*16+l16)*64 + sl];
      #pragma unroll
      for (int in=0;in<8;in++)
        acc[in] = __builtin_amdgcn_mfma_f32_16x16x32_bf16(af, bfr[in], acc[in], 0, 0, 0);
    }
  };

  constexpr int NIT = KTOT / 64;
  STAGE(0, 0);
  #pragma unroll
  for (int t = 0; t < NIT; ++t) {
    __builtin_amdgcn_sched_barrier(0);
    asm volatile("s_waitcnt vmcnt(0) lgkmcnt(0)" ::: "memory");
    __builtin_amdgcn_s_barrier();
    __builtin_amdgcn_sched_barrier(0);
    if (t + 1 < NIT) STAGE((t+1)*64, (t+1)&1);
    COMPUTE(t&1);
  }
  __syncthreads();            // staging bufs free -> smem reuse for epilogue

  if (EPI == 1 || EPI == 2) {
    u16* tile = smem; // [128 m][128 o], 32KB
    #pragma unroll
    for (int in=0;in<8;in++){
      int ol = in*16 + l16;
      float sc = scale[o0+ol], bi = bias[o0+ol];
      #pragma unroll
      for (int r=0;r<4;r++){
        float v = acc[in][r]*sc + bi;
        if (EPI==2) v = gelu_f(v);
        tile[(wid*16+quad*4+r)*128 + ol] = f2b(v);
      }
    }
    __syncthreads();
    u16* op = (u16*)outp;
    #pragma unroll
    for (int p=0;p<4;p++){
      int chunk = p*512 + tid;
      int rr = chunk >> 4, off = (chunk & 15)*8;
      *(uint4*)&op[((size_t)(m0 + rr))*CAT_LD + o0 + off] = *(const uint4*)&tile[rr*128 + off];
    }
  } else {
    float* ftile = (float*)smem; // [64 o][132 m] fp32 = 33792B, one half at a time
    float* op = (float*)outp;
    #pragma unroll
    for (int h=0; h<2; h++){
      #pragma unroll
      for (int in4=0;in4<4;in4++){
        int in = h*4 + in4;
        int c64 = in4*16 + l16;
        int og = o0 + h*64 + c64;
        float sc = scale[og], bi = bias[og];
        float4v v;
        #pragma unroll
        for (int r=0;r<4;r++) v[r] = acc[in][r]*sc + bi;
        *(float4v*)&ftile[c64*132 + wid*16 + quad*4] = v;
      }
      __syncthreads();
      #pragma unroll
      for (int p=0;p<4;p++){
        int chunk = p*512 + tid;
        int rr = chunk >> 5, off = (chunk & 31)*4;
        int m = m0 + off;
        int b = m / SPB, s = m - b*SPB;
        size_t g = ((size_t)(b*256 + o0 + h*64 + rr))*SPB + s;
        float4v v = *(const float4v*)&ftile[rr*132 + off];
        v.x += resid[g]; v.y += resid[g+1]; v.z += resid[g+2]; v.w += resid[g+3];
        *(float4v*)&op[g] = v;
      }
      __syncthreads();
    }
  }
}

extern "C" void kernel_launch(void* const* d_in, const int* in_sizes, int n_in,
                              void* d_out, int out_size, void* d_ws, size_t ws_size,
                              hipStream_t stream)
{
  const float* x  = (const float*)d_in[0];
  const float* w1 = (const float*)d_in[1];
  const float* b1 = (const float*)d_in[2];
  const float* g1 = (const float*)d_in[3];
  const float* be1= (const float*)d_in[4];
  const float* m1 = (const float*)d_in[5];
  const float* v1 = (const float*)d_in[6];
  const float* wg = (const float*)d_in[7];
  const float* bg = (const float*)d_in[8];
  const float* gg = (const float*)d_in[9];
  const float* beg= (const float*)d_in[10];
  const float* mg = (const float*)d_in[11];
  const float* vg = (const float*)d_in[12];
  const float* w2 = (const float*)d_in[13];
  const float* b2 = (const float*)d_in[14];
  const float* g2 = (const float*)d_in[15];
  const float* be2= (const float*)d_in[16];
  const float* m2 = (const float*)d_in[17];
  const float* v2 = (const float*)d_in[18];

  char* ws = (char*)d_ws;
  size_t off = 0;
  auto alloc = [&](size_t bytes){ void* p = ws + off; off += (bytes + 255) & ~(size_t)255; return p; };
  u16* xt    = (u16*)alloc((size_t)MTOT*XT_LD*2);    // x transposed, bf16, padded
  u16* catt  = (u16*)alloc((size_t)MTOT*CAT_LD*2);   // [h ; xj], bf16, padded
  u16* gt    = (u16*)alloc((size_t)MTOT*CAT_LD*2);   // gelu output, bf16, padded
  u16* w1b   = (u16*)alloc((size_t)256*XT_LD*2);
  u16* wgb   = (u16*)alloc((size_t)512*CAT_LD*2);
  u16* w2b   = (u16*)alloc((size_t)256*CAT_LD*2);
  float* cst = (float*)alloc((size_t)2048*4);

  hipLaunchKernelGGL(prep_k, dim3(98,8,10), dim3(32,8), 0, stream,
                     x, xt, w1,wg,w2, b1,g1,be1,m1,v1, bg,gg,beg,mg,vg, b2,g2,be2,m2,v2,
                     w1b,wgb,w2b, cst);
  hipLaunchKernelGGL((gemm_k<256,XT_LD,XT_LD,1>), dim3(196,2), dim3(512), 0, stream,
                     xt, w1b, cst+0, cst+256, (void*)catt, (const float*)nullptr);
  hipLaunchKernelGGL(hxj_k, dim3(32, NB), dim3(448), 0, stream, catt);
  hipLaunchKernelGGL((gemm_k<512,CAT_LD,CAT_LD,2>), dim3(196,4), dim3(512), 0, stream,
                     catt, wgb, cst+512, cst+1024, (void*)gt, (const float*)nullptr);
  hipLaunchKernelGGL((gemm_k<512,CAT_LD,CAT_LD,3>), dim3(196,2), dim3(512), 0, stream,
                     gt, w2b, cst+1536, cst+1792, d_out, x);
}

// Round 12
// 175.967 us; speedup vs baseline: 1.1694x; 1.0804x over previous
//
#include <hip/hip_runtime.h>
#include <math.h>

#define SPB 3136      // spatial positions per batch (56*56)
#define NB 8
#define MTOT (NB*SPB) // 25088 = 196*128, flattened M across batch
#define EPS 1e-5f
// padded leading dims (u16 elems): +32 bf16 = +64B so row strides are ODD
// multiples of 64B -> walk all L2 channels (break 512B/1KB channel aliasing)
#define XT_LD  288    // xt rows (K=256)
#define CAT_LD 544    // catt/gt rows (K=512)

typedef unsigned short u16;
typedef __attribute__((ext_vector_type(8))) short short8;
typedef __attribute__((ext_vector_type(4))) float float4v;

__device__ __forceinline__ float b2f(u16 v){ unsigned u=((unsigned)v)<<16; float f; __builtin_memcpy(&f,&u,4); return f; }
__device__ __forceinline__ u16 f2b(float f){ unsigned u; __builtin_memcpy(&u,&f,4); u += 0x7fffu + ((u>>16)&1u); return (u16)(u>>16); }
// tanh-approx GELU via sigmoid
__device__ __forceinline__ float gelu_f(float z){
  float t = 1.5957691216f * z * (1.0f + 0.044715f*z*z);
  return __fdividef(z, 1.0f + __expf(-t));
}

// async global->LDS, 16B per lane; lds dest must be wave-uniform base + lane*16
__device__ __forceinline__ void gll16(const u16* g, u16* l){
  __builtin_amdgcn_global_load_lds((const __attribute__((address_space(1))) void*)g,
                                   (__attribute__((address_space(3))) void*)l, 16, 0, 0);
}

// ---- fused prep: x transpose (blocks z<8) + weight bf16 (PADDED rows) + BN consts (z>=8) ----
// cst layout: s1[256] t1[256] sg[512] tg[512] s2[256] t2[256]
__global__ void prep_k(const float* __restrict__ x, u16* __restrict__ xt,
                       const float* __restrict__ w1,const float* __restrict__ wg,const float* __restrict__ w2,
                       const float* b1,const float* g1,const float* be1,const float* m1,const float* v1,
                       const float* bg,const float* gg,const float* beg,const float* mg,const float* vg,
                       const float* b2,const float* g2,const float* be2,const float* m2,const float* v2,
                       u16* __restrict__ w1b,u16* __restrict__ wgb,u16* __restrict__ w2b,float* cst){
  __shared__ float t[32][33];
  if (blockIdx.z < 8) {
    int b = blockIdx.z, ct = blockIdx.y, st = blockIdx.x;
    int ts = threadIdx.x, tc = threadIdx.y;
    #pragma unroll
    for (int i=0;i<4;i++){
      int c = tc + i*8;
      t[c][ts] = x[((size_t)(b*256 + ct*32 + c))*SPB + st*32 + ts];
    }
    __syncthreads();
    #pragma unroll
    for (int i=0;i<4;i++){
      int r = tc + i*8;
      xt[((size_t)(b*SPB + st*32 + r))*XT_LD + ct*32 + ts] = f2b(t[ts][r]);
    }
  } else {
    int tid = threadIdx.y*32 + threadIdx.x;
    int w = ((blockIdx.z-8)*8 + blockIdx.y)*98 + blockIdx.x;   // [0, 1568)
    int i = w*256 + tid;
    if (i < 65536)  w1b[(i>>8)*XT_LD  + (i&255)] = f2b(w1[i]);   // [256][256] -> LD 288
    if (i < 262144) wgb[(i>>9)*CAT_LD + (i&511)] = f2b(wg[i]);   // [512][512] -> LD 544
    if (i < 131072) w2b[(i>>9)*CAT_LD + (i&511)] = f2b(w2[i]);   // [256][512] -> LD 544
    if (i < 256) {
      float s = g1[i]*rsqrtf(v1[i]+EPS);
      cst[i] = s; cst[256+i] = b1[i]*s + be1[i] - m1[i]*s;
      float s2 = g2[i]*rsqrtf(v2[i]+EPS);
      cst[1536+i] = s2; cst[1792+i] = b2[i]*s2 + be2[i] - m2[i]*s2;
    }
    if (i < 512) {
      float s = gg[i]*rsqrtf(vg[i]+EPS);
      cst[512+i] = s; cst[1024+i] = bg[i]*s + beg[i] - mg[i]*s;
    }
  }
}

// fused row/col parity-min over h = cat[...,0:256], 8 channels/thread, short8.
// (R9-verified: split two-kernel min/xj beats the fused 1-block/CU version by 12.5us)
__global__ __launch_bounds__(256) void minmax_k(const u16* __restrict__ cat, float* __restrict__ rmin, float* __restrict__ cmin){
  __shared__ float red[8][256];
  int b = blockIdx.x/56, i = blockIdx.x%56;
  int col = blockIdx.y;
  int slice = threadIdx.x >> 5;
  int c0 = (threadIdx.x & 31) * 8;
  const u16* base; size_t stride;
  if (!col){ base = cat + ((size_t)(b*SPB + i*56))*CAT_LD + c0; stride = CAT_LD; }
  else     { base = cat + ((size_t)(b*SPB + i))*CAT_LD + c0;    stride = (size_t)56*CAT_LD; }
  float m[8];
  #pragma unroll
  for (int k=0;k<8;k++) m[k]=3.4e38f;
  #pragma unroll
  for (int jj=0;jj<7;jj++){
    short8 v = *(const short8*)(base + (size_t)(slice + jj*8)*stride);
    #pragma unroll
    for (int k=0;k<8;k++) m[k] = fminf(m[k], b2f((u16)v[k]));
  }
  #pragma unroll
  for (int k=0;k<8;k++) red[slice][c0+k] = m[k];
  __syncthreads();
  int t = threadIdx.x;
  if (t < 64){
    int par = t >> 5;
    int cc = (t & 31) * 8;
    float* out = col ? cmin : rmin;
    float* p = &out[((size_t)(b*2+par)*56 + i)*256 + cc];
    #pragma unroll
    for (int k=0;k<8;k++)
      p[k] = fminf(fminf(red[par][cc+k], red[par+2][cc+k]),
                   fminf(red[par+4][cc+k], red[par+6][cc+k]));
  }
}

// xj = max(0, h - min(colMinP[y%2][x], rowMinP[x%2][y])) -> cat[...,256:512]
__global__ __launch_bounds__(256) void xj_k(u16* __restrict__ cat, const float* __restrict__ rmin, const float* __restrict__ cmin){
  int b = blockIdx.y;
  int t = threadIdx.x;
  int s = blockIdx.x*8 + (t>>5);
  int c0 = (t&31)*8;
  int y = s/56, x = s%56;
  size_t idx = ((size_t)(b*SPB + s))*CAT_LD;
  short8 h8 = *(const short8*)&cat[idx + c0];
  const float* cp = &cmin[((size_t)(b*2+(y&1))*56 + x)*256 + c0];
  const float* rp = &rmin[((size_t)(b*2+(x&1))*56 + y)*256 + c0];
  float4v cv0 = *(const float4v*)cp, cv1 = *(const float4v*)(cp+4);
  float4v rv0 = *(const float4v*)rp, rv1 = *(const float4v*)(rp+4);
  short8 o;
  #pragma unroll
  for (int j=0;j<8;j++){
    float cm = (j<4) ? cv0[j] : cv1[j-4];
    float rm = (j<4) ? rv0[j] : rv1[j-4];
    o[j] = (short)f2b(fmaxf(0.0f, b2f((u16)h8[j]) - fminf(cm, rm)));
  }
  *(short8*)&cat[idx + 256 + c0] = o;
}

// bijective XCD-chunk remap (T1, m204); all gemm grids are %8==0
__device__ __forceinline__ int xcd_remap(int orig, int nwg){
  int q = nwg >> 3, r = nwg & 7, xc = orig & 7, rest = orig >> 3;
  int base = (xc < r) ? xc*(q+1) : r*(q+1) + (xc-r)*q;
  return base + rest;
}

// GEMM (R9-verified 177.6us config): BK=64, 2 bufs x 32KB = 64KB
// -> 2 blocks/CU (inter-block overlap covers the barrier drain; R10/R11
// proved 1 block/CU loses ~12us).  BM=BN=128, 512 thr = 8 waves, wave 16m x 128o.
//   top of iter: sched_barrier; vmcnt(0) lgkmcnt(0); s_barrier; sched_barrier;
//   then STAGE(t+1) -> buf (t+1)&1; COMPUTE(t) -> buf t&1.
// lgkmcnt(0) before barrier: COMPUTE(t-1)'s reads of buf (t-1)&1 (= the buf
// STAGE(t+1) overwrites) complete before any wave crosses (R3 discipline).
// Staging (8 slots/row): thread t -> rows (t>>3), 64+(t>>3), slot t&7;
// gll16 dest = tid*16B (lane-linear). T2 both-sides: source chunk
// (t&7)^((t>>3)&7); read slot (kk*4+quad)^(l16&7). Row terms = 0 mod 8.
// EPI 1: bf16(acc*s+t)        -> out [m][CAT_LD] at col o0
// EPI 2: bf16(gelu(acc*s+t))  -> out [m][CAT_LD] at col o0
// EPI 3: fp32(acc*s+t + resid[b][o][s]) -> out [b][256][s]
template<int KTOT, int LDA, int LDB, int EPI>
__global__ __launch_bounds__(512,4) void gemm_k(
    const u16* __restrict__ Ain, const u16* __restrict__ Wt,
    const float* __restrict__ scale, const float* __restrict__ bias,
    void* __restrict__ outp, const float* __restrict__ resid)
{
  __shared__ __align__(16) u16 smem[32768];   // 65536 B: 2 x 32KB staging / epilogue union
  const int tid = threadIdx.x;
  const int nwg = gridDim.x * gridDim.y;
  const int flat = blockIdx.y * gridDim.x + blockIdx.x;
  const int s_ = xcd_remap(flat, nwg);
  const int m0 = (s_ / gridDim.y) * 128;
  const int o0 = (s_ % gridDim.y) * 128;
  const int lane = tid & 63, wid = tid >> 6;     // 8 waves
  const int quad = lane >> 4, l16 = lane & 15;

  float4v acc[8];
  #pragma unroll
  for (int j=0;j<8;j++) acc[j] = (float4v){0.f,0.f,0.f,0.f};

  // staging buf at smem + buf*16384 (u16): A [128][64] +0, B [128][64] +8192.
  const int row8 = tid >> 3;                       // 0..63
  const int gc   = ((tid & 7) ^ (row8 & 7)) * 8;   // T2 source chunk (u16 off)
  const u16* ga0 = Ain + ((size_t)(m0 + row8))*LDA + gc;
  const u16* ga1 = ga0 + (size_t)64*LDA;
  const u16* gb0 = Wt  + ((size_t)(o0 + row8))*LDB + gc;
  const u16* gb1 = gb0 + (size_t)64*LDB;
  u16* l8 = smem + tid*8;

  auto STAGE = [&](int kt, int buf){
    u16* b_ = l8 + buf*16384;
    gll16(ga0 + kt, b_);
    gll16(ga1 + kt, b_ + 4096);
    gll16(gb0 + kt, b_ + 8192);
    gll16(gb1 + kt, b_ + 12288);
  };
  const int r7 = l16 & 7;                          // read-row & 7 (all frag rows)
  auto COMPUTE = [&](int buf){
    const u16* A_ = smem + buf*16384;
    const u16* B_ = A_ + 8192;
    #pragma unroll
    for (int kk=0; kk<2; kk++){
      const int sl = ((kk*4 + quad) ^ r7) * 8;
      short8 af = *(const short8*)&A_[(wid*16 + l16)*64 + sl];
      short8 bfr[8];
      #pragma unroll
      for (int in=0;in<8;in++) bfr[in] = *(const short8*)&B_[(in*16+l16)*64 + sl];
      #pragma unroll
      for (int in=0;in<8;in++)
        acc[in] = __builtin_amdgcn_mfma_f32_16x16x32_bf16(af, bfr[in], acc[in], 0, 0, 0);
    }
  };

  constexpr int NIT = KTOT / 64;
  STAGE(0, 0);
  #pragma unroll
  for (int t = 0; t < NIT; ++t) {
    __builtin_amdgcn_sched_barrier(0);
    asm volatile("s_waitcnt vmcnt(0) lgkmcnt(0)" ::: "memory");
    __builtin_amdgcn_s_barrier();
    __builtin_amdgcn_sched_barrier(0);
    if (t + 1 < NIT) STAGE((t+1)*64, (t+1)&1);
    COMPUTE(t&1);
  }
  __syncthreads();            // staging bufs free -> smem reuse for epilogue

  if (EPI == 1 || EPI == 2) {
    u16* tile = smem; // [128 m][128 o], 32KB
    #pragma unroll
    for (int in=0;in<8;in++){
      int ol = in*16 + l16;
      float sc = scale[o0+ol], bi = bias[o0+ol];
      #pragma unroll
      for (int r=0;r<4;r++){
        float v = acc[in][r]*sc + bi;
        if (EPI==2) v = gelu_f(v);
        tile[(wid*16+quad*4+r)*128 + ol] = f2b(v);
      }
    }
    __syncthreads();
    u16* op = (u16*)outp;
    #pragma unroll
    for (int p=0;p<4;p++){
      int chunk = p*512 + tid;
      int rr = chunk >> 4, off = (chunk & 15)*8;
      *(uint4*)&op[((size_t)(m0 + rr))*CAT_LD + o0 + off] = *(const uint4*)&tile[rr*128 + off];
    }
  } else {
    float* ftile = (float*)smem; // [64 o][132 m] fp32 = 33792B, one half at a time
    float* op = (float*)outp;
    #pragma unroll
    for (int h=0; h<2; h++){
      #pragma unroll
      for (int in4=0;in4<4;in4++){
        int in = h*4 + in4;
        int c64 = in4*16 + l16;
        int og = o0 + h*64 + c64;
        float sc = scale[og], bi = bias[og];
        float4v v;
        #pragma unroll
        for (int r=0;r<4;r++) v[r] = acc[in][r]*sc + bi;
        *(float4v*)&ftile[c64*132 + wid*16 + quad*4] = v;
      }
      __syncthreads();
      #pragma unroll
      for (int p=0;p<4;p++){
        int chunk = p*512 + tid;
        int rr = chunk >> 5, off = (chunk & 31)*4;
        int m = m0 + off;
        int b = m / SPB, s = m - b*SPB;
        size_t g = ((size_t)(b*256 + o0 + h*64 + rr))*SPB + s;
        float4v v = *(const float4v*)&ftile[rr*132 + off];
        v.x += resid[g]; v.y += resid[g+1]; v.z += resid[g+2]; v.w += resid[g+3];
        *(float4v*)&op[g] = v;
      }
      __syncthreads();
    }
  }
}

extern "C" void kernel_launch(void* const* d_in, const int* in_sizes, int n_in,
                              void* d_out, int out_size, void* d_ws, size_t ws_size,
                              hipStream_t stream)
{
  const float* x  = (const float*)d_in[0];
  const float* w1 = (const float*)d_in[1];
  const float* b1 = (const float*)d_in[2];
  const float* g1 = (const float*)d_in[3];
  const float* be1= (const float*)d_in[4];
  const float* m1 = (const float*)d_in[5];
  const float* v1 = (const float*)d_in[6];
  const float* wg = (const float*)d_in[7];
  const float* bg = (const float*)d_in[8];
  const float* gg = (const float*)d_in[9];
  const float* beg= (const float*)d_in[10];
  const float* mg = (const float*)d_in[11];
  const float* vg = (const float*)d_in[12];
  const float* w2 = (const float*)d_in[13];
  const float* b2 = (const float*)d_in[14];
  const float* g2 = (const float*)d_in[15];
  const float* be2= (const float*)d_in[16];
  const float* m2 = (const float*)d_in[17];
  const float* v2 = (const float*)d_in[18];

  char* ws = (char*)d_ws;
  size_t off = 0;
  auto alloc = [&](size_t bytes){ void* p = ws + off; off += (bytes + 255) & ~(size_t)255; return p; };
  u16* xt    = (u16*)alloc((size_t)MTOT*XT_LD*2);    // x transposed, bf16, padded
  u16* catt  = (u16*)alloc((size_t)MTOT*CAT_LD*2);   // [h ; xj], bf16, padded
  u16* gt    = (u16*)alloc((size_t)MTOT*CAT_LD*2);   // gelu output, bf16, padded
  u16* w1b   = (u16*)alloc((size_t)256*XT_LD*2);
  u16* wgb   = (u16*)alloc((size_t)512*CAT_LD*2);
  u16* w2b   = (u16*)alloc((size_t)256*CAT_LD*2);
  float* cst = (float*)alloc((size_t)2048*4);
  float* rmin= (float*)alloc((size_t)NB*2*56*256*4);
  float* cmin= (float*)alloc((size_t)NB*2*56*256*4);

  hipLaunchKernelGGL(prep_k, dim3(98,8,10), dim3(32,8), 0, stream,
                     x, xt, w1,wg,w2, b1,g1,be1,m1,v1, bg,gg,beg,mg,vg, b2,g2,be2,m2,v2,
                     w1b,wgb,w2b, cst);
  hipLaunchKernelGGL((gemm_k<256,XT_LD,XT_LD,1>), dim3(196,2), dim3(512), 0, stream,
                     xt, w1b, cst+0, cst+256, (void*)catt, (const float*)nullptr);
  hipLaunchKernelGGL(minmax_k, dim3(NB*56,2), dim3(256), 0, stream, catt, rmin, cmin);
  hipLaunchKernelGGL(xj_k, dim3(392, NB), dim3(256), 0, stream, catt, rmin, cmin);
  hipLaunchKernelGGL((gemm_k<512,CAT_LD,CAT_LD,2>), dim3(196,4), dim3(512), 0, stream,
                     catt, wgb, cst+512, cst+1024, (void*)gt, (const float*)nullptr);
  hipLaunchKernelGGL((gemm_k<512,CAT_LD,CAT_LD,3>), dim3(196,2), dim3(512), 0, stream,
                     gt, w2b, cst+1536, cst+1792, d_out, x);
}